// Round 2
// baseline (3164.616 us; speedup 1.0000x reference)
//
#include <hip/hip_runtime.h>
#include <math.h>

#define Hn   256
#define En   128
#define Vn   256
#define TPn  32
#define BTn  2048
#define NSV  8              // seqs per WG
#define NWG  (BTn / NSV)    // 256 workgroups
#define NT   1024           // 16 waves
#define HROW 272            // padded LDS row stride (floats) for h
#define SROW 260            // padded LDS row stride for score stage

// physical index within an h row: +4 float skew per 64-chunk (conflict-free quads)
__device__ __forceinline__ int hp(int k) { return k + 4 * (k >> 6); }

__device__ __forceinline__ float sigf(float x) {
    return __builtin_amdgcn_rcpf(1.0f + __expf(-x));
}
__device__ __forceinline__ float tanh_fast(float x) {
    float e = __expf(2.0f * x);
    return 1.0f - 2.0f * __builtin_amdgcn_rcpf(e + 1.0f);
}

__device__ __forceinline__ unsigned long long amax_key(float sc, int v) {
    unsigned fb = __float_as_uint(sc);
    fb = (fb & 0x80000000u) ? ~fb : (fb | 0x80000000u);   // order-preserving
    return ((unsigned long long)fb << 32) | (unsigned)(Vn - 1 - v);  // first-idx tie
}
__device__ __forceinline__ float dot4(float4 a, float4 b, float acc) {
    return fmaf(a.x, b.x, fmaf(a.y, b.y, fmaf(a.z, b.z, fmaf(a.w, b.w, acc))));
}

// Butterfly reduce-scatter over the 4 K-chunk lanes (ch = lane&3).
// In: v[0..7] = partial sums for seqs 0..7 (this lane's K-chunk).
// Out: a = full sum for seq 2ch, b = full sum for seq 2ch+1. Static regs only.
__device__ __forceinline__ void rs8(const float v[8], int ch, float& a, float& b) {
    const bool hi2 = (ch & 2) != 0;
    float w0, w1, w2, w3;
    { float s = hi2 ? v[0] : v[4]; float r = __shfl_xor(s, 2, 64); w0 = (hi2 ? v[4] : v[0]) + r; }
    { float s = hi2 ? v[1] : v[5]; float r = __shfl_xor(s, 2, 64); w1 = (hi2 ? v[5] : v[1]) + r; }
    { float s = hi2 ? v[2] : v[6]; float r = __shfl_xor(s, 2, 64); w2 = (hi2 ? v[6] : v[2]) + r; }
    { float s = hi2 ? v[3] : v[7]; float r = __shfl_xor(s, 2, 64); w3 = (hi2 ? v[7] : v[3]) + r; }
    const bool hi1 = (ch & 1) != 0;
    { float s = hi1 ? w0 : w2; float r = __shfl_xor(s, 1, 64); a = (hi1 ? w2 : w0) + r; }
    { float s = hi1 ? w1 : w3; float r = __shfl_xor(s, 1, 64); b = (hi1 ? w3 : w1) + r; }
}

// ---------------- precompute kernels ----------------

// Ptu[v*256+u] = float4{i,f,g,o}: emb[v]@Wih[g*256+u]^T + bih + bhh
__global__ void make_ptab(float4* __restrict__ Pp, const float* __restrict__ emb,
                          const float* __restrict__ Wih, const float* __restrict__ bih,
                          const float* __restrict__ bhh) {
    int v = blockIdx.x, u = threadIdx.x;
    __shared__ __align__(16) float es[En];
    if (u < En) es[u] = emb[v * En + u];
    __syncthreads();
    float a[4];
#pragma unroll
    for (int g = 0; g < 4; ++g) {
        int r = g * Hn + u;
        float acc = bih[r] + bhh[r];
        const float4* w4 = (const float4*)(Wih + r * En);
        const float4* e4 = (const float4*)es;
        for (int k = 0; k < En / 4; ++k) acc = dot4(w4[k], e4[k], acc);
        a[g] = acc;
    }
    Pp[v * Hn + u] = make_float4(a[0], a[1], a[2], a[3]);
}

// Wr[(j4*4+g)*1024 + (u*4+ch)] = float4{ Whh[g*256+u][ch*64+4j4 .. +3] }. 65536 f4.
__global__ void pack_wr(float4* __restrict__ Wr, const float* __restrict__ W) {
    int idx = blockIdx.x * 256 + threadIdx.x;
    int l = idx & 1023, stripe = idx >> 10;     // stripe 0..63
    int j4 = stripe >> 2, g = stripe & 3;
    int u = l >> 2, ch = l & 3;
    const float* s = W + (g * Hn + u) * Hn + ch * 64 + 4 * j4;
    Wr[idx] = make_float4(s[0], s[1], s[2], s[3]);
}

// Fr[j4*1024 + (u*4+ch)] = float4{ fcW[u][ch*64+4j4 .. +3] }. 16384 f4.
__global__ void pack_fr(float4* __restrict__ Fr, const float* __restrict__ W) {
    int idx = blockIdx.x * 256 + threadIdx.x;
    int l = idx & 1023, j4 = idx >> 10;
    int u = l >> 2, ch = l & 3;
    const float* s = W + u * Hn + ch * 64 + 4 * j4;
    Fr[idx] = make_float4(s[0], s[1], s[2], s[3]);
}

// ---------------- encoder ----------------
// 256 WGs x 1024 thr. Thread (u=tid>>2, ch=tid&3): gate rows 4u..4u+3 over
// K-chunk ch for all 8 seqs; reduce-scatter -> seqs {2ch,2ch+1} lane-local.
__global__ __launch_bounds__(NT, 4) void enc_kernel(
    const float4* __restrict__ Wr, const float4* __restrict__ Ptu,
    const int* __restrict__ phon, const int* __restrict__ lens,
    float* __restrict__ h0dec) {
    const int tid = threadIdx.x, wg = blockIdx.x;
    const int u = tid >> 2, ch = tid & 3;
    const int sA = 2 * ch, sB = 2 * ch + 1;
    __shared__ __align__(16) float hs[NSV * HROW];
    __shared__ int lsh[NSV];

    for (int i = tid; i < NSV * HROW; i += NT) hs[i] = 0.0f;
    if (tid < NSV) lsh[tid] = lens[wg * NSV + tid];
    float cA = 0.f, cB = 0.f;
    __syncthreads();
    int mx = 0;
#pragma unroll
    for (int i = 0; i < NSV; ++i) mx = max(mx, lsh[i]);
    const int lenA = lsh[sA], lenB = lsh[sB];

    for (int t = 0; t < mx; ++t) {
        const int tokA = phon[(wg * NSV + sA) * TPn + t];
        const int tokB = phon[(wg * NSV + sB) * TPn + t];
        const float4 pA = Ptu[tokA * Hn + u];      // prefetched; hidden by K-loop
        const float4 pB = Ptu[tokB * Hn + u];
        float ag[4][8];
#pragma unroll
        for (int g = 0; g < 4; ++g)
#pragma unroll
            for (int s = 0; s < 8; ++s) ag[g][s] = 0.0f;
        const float* hb = hs + ch * 68;
#pragma unroll
        for (int j4 = 0; j4 < 16; ++j4) {
            float4 w0 = Wr[(j4 * 4 + 0) * NT + tid];
            float4 w1 = Wr[(j4 * 4 + 1) * NT + tid];
            float4 w2 = Wr[(j4 * 4 + 2) * NT + tid];
            float4 w3 = Wr[(j4 * 4 + 3) * NT + tid];
#pragma unroll
            for (int s = 0; s < 8; ++s) {
                float4 hv = *(const float4*)&hb[s * HROW + 4 * j4];
                ag[0][s] = dot4(w0, hv, ag[0][s]);
                ag[1][s] = dot4(w1, hv, ag[1][s]);
                ag[2][s] = dot4(w2, hv, ag[2][s]);
                ag[3][s] = dot4(w3, hv, ag[3][s]);
            }
        }
        float gA[4], gB[4];
#pragma unroll
        for (int g = 0; g < 4; ++g) rs8(ag[g], ch, gA[g], gB[g]);
        __syncthreads();   // all K-reads of hs done
        float hA, hB;
        {
            float gi = sigf(gA[0] + pA.x), gf = sigf(gA[1] + pA.y);
            float gg = tanh_fast(gA[2] + pA.z), go = sigf(gA[3] + pA.w);
            cA = fmaf(gf, cA, gi * gg); hA = go * tanh_fast(cA);
        }
        {
            float gi = sigf(gB[0] + pB.x), gf = sigf(gB[1] + pB.y);
            float gg = tanh_fast(gB[2] + pB.z), go = sigf(gB[3] + pB.w);
            cB = fmaf(gf, cB, gi * gg); hB = go * tanh_fast(cB);
        }
        const int pu = hp(u);
        hs[sA * HROW + pu] = hA;
        hs[sB * HROW + pu] = hB;
        if (t == lenA - 1) h0dec[(wg * NSV + sA) * Hn + u] = hA;
        if (t == lenB - 1) h0dec[(wg * NSV + sB) * Hn + u] = hB;
        __syncthreads();   // new h visible
    }
}

// ---------------- decoder ----------------
// Iteration i: fc(h_i) -> scores_{i-1} -> argmax -> tok_i; gates(h_i,tok_i) -> h_{i+1}.
// Two barriers/iter: argmax via parity-double-buffered LDS atomicMax (u64 keys).
__global__ __launch_bounds__(NT, 4) void dec_kernel(
    const float4* __restrict__ Wr, const float4* __restrict__ Fr,
    const float4* __restrict__ Ptu, const float* __restrict__ fcb,
    const float* __restrict__ h0dec, const int* __restrict__ sosp,
    float* __restrict__ out) {
    const int tid = threadIdx.x, wg = blockIdx.x;
    const int u = tid >> 2, ch = tid & 3;
    const int sA = 2 * ch, sB = 2 * ch + 1;
    const int ln = tid & 63;
    __shared__ __align__(16) float hs[NSV * HROW];
    __shared__ __align__(16) float scx[NSV * SROW];
    __shared__ unsigned long long gmax[2][NSV];

    {   // stage h0
        int s = tid >> 7, k = (tid & 127) * 2;
        float2 v = *(const float2*)&h0dec[(wg * NSV + s) * Hn + k];
        int pk = hp(k);
        hs[s * HROW + pk] = v.x;
        hs[s * HROW + pk + 1] = v.y;
    }
    if (tid < 2 * NSV) ((unsigned long long*)gmax)[tid] = 0ull;
    const int sos0 = sosp[0];
    const float fb = fcb[u];
    float cA = 0.f, cB = 0.f;
    __syncthreads();

    for (int i = 0; i <= TPn; ++i) {
        const bool full = (i < TPn);
        float ag[4][8], af[8];
#pragma unroll
        for (int g = 0; g < 4; ++g)
#pragma unroll
            for (int s = 0; s < 8; ++s) ag[g][s] = 0.0f;
#pragma unroll
        for (int s = 0; s < 8; ++s) af[s] = 0.0f;
        const float* hb = hs + ch * 68;
        if (full) {
#pragma unroll
            for (int j4 = 0; j4 < 16; ++j4) {
                float4 w0 = Wr[(j4 * 4 + 0) * NT + tid];
                float4 w1 = Wr[(j4 * 4 + 1) * NT + tid];
                float4 w2 = Wr[(j4 * 4 + 2) * NT + tid];
                float4 w3 = Wr[(j4 * 4 + 3) * NT + tid];
                float4 f = Fr[j4 * NT + tid];
#pragma unroll
                for (int s = 0; s < 8; ++s) {
                    float4 hv = *(const float4*)&hb[s * HROW + 4 * j4];
                    ag[0][s] = dot4(w0, hv, ag[0][s]);
                    ag[1][s] = dot4(w1, hv, ag[1][s]);
                    ag[2][s] = dot4(w2, hv, ag[2][s]);
                    ag[3][s] = dot4(w3, hv, ag[3][s]);
                    af[s] = dot4(f, hv, af[s]);
                }
            }
        } else {   // last iteration: fc only
#pragma unroll
            for (int j4 = 0; j4 < 16; ++j4) {
                float4 f = Fr[j4 * NT + tid];
#pragma unroll
                for (int s = 0; s < 8; ++s) {
                    float4 hv = *(const float4*)&hb[s * HROW + 4 * j4];
                    af[s] = dot4(f, hv, af[s]);
                }
            }
        }
        float gA[4], gB[4], fA, fB;
#pragma unroll
        for (int g = 0; g < 4; ++g) rs8(ag[g], ch, gA[g], gB[g]);
        rs8(af, ch, fA, fB);

        if (i > 0) {   // scores_{i-1} for v=u, seqs sA,sB
            float scA = fA + fb, scB = fB + fb;
            scx[sA * SROW + u] = scA;
            scx[sB * SROW + u] = scB;
            unsigned long long kA = amax_key(scA, u);
            unsigned long long kB = amax_key(scB, u);
#pragma unroll
            for (int off = 4; off < 64; off <<= 1) {
                unsigned long long oA = __shfl_xor(kA, off, 64);
                unsigned long long oB = __shfl_xor(kB, off, 64);
                if (oA > kA) kA = oA;
                if (oB > kB) kB = oB;
            }
            if (ln < 4) {          // ln==ch here: one representative per wave per seq
                atomicMax(&gmax[i & 1][sA], kA);
                atomicMax(&gmax[i & 1][sB], kB);
            }
        }
        __syncthreads();   // bar1: hs reads done; scx + gmax[i&1] visible

        int tokA = sos0, tokB = sos0;
        if (i > 0) {
            {   // coalesced out store of scores_{i-1}
                int s = tid >> 7, k = (tid & 127) * 2;
                float2 v = *(const float2*)&scx[s * SROW + k];
                *(float2*)&out[((long)(wg * NSV + s) * TPn + (i - 1)) * Vn + k] = v;
            }
            tokA = (Vn - 1) - (int)(gmax[i & 1][sA] & 0xffffffffu);
            tokB = (Vn - 1) - (int)(gmax[i & 1][sB] & 0xffffffffu);
            if (tid < NSV) gmax[(i + 1) & 1][tid] = 0ull;   // reset other parity slot
        }

        if (full) {
            const float4 pA = Ptu[tokA * Hn + u];
            const float4 pB = Ptu[tokB * Hn + u];
            float hA, hB;
            {
                float gi = sigf(gA[0] + pA.x), gf = sigf(gA[1] + pA.y);
                float gg = tanh_fast(gA[2] + pA.z), go = sigf(gA[3] + pA.w);
                cA = fmaf(gf, cA, gi * gg); hA = go * tanh_fast(cA);
            }
            {
                float gi = sigf(gB[0] + pB.x), gf = sigf(gB[1] + pB.y);
                float gg = tanh_fast(gB[2] + pB.z), go = sigf(gB[3] + pB.w);
                cB = fmaf(gf, cB, gi * gg); hB = go * tanh_fast(cB);
            }
            const int pu = hp(u);
            hs[sA * HROW + pu] = hA;
            hs[sB * HROW + pu] = hB;
        }
        __syncthreads();   // bar2: new h + gmax reset visible
    }
}

// ---------------- launch ----------------
extern "C" void kernel_launch(void* const* d_in, const int* in_sizes, int n_in,
                              void* d_out, int out_size, void* d_ws, size_t ws_size,
                              hipStream_t stream) {
    const int*   phon = (const int*)d_in[0];
    const int*   lens = (const int*)d_in[1];
    const float* emb  = (const float*)d_in[2];
    const float* eWih = (const float*)d_in[3];
    const float* eWhh = (const float*)d_in[4];
    const float* ebih = (const float*)d_in[5];
    const float* ebhh = (const float*)d_in[6];
    const float* dWih = (const float*)d_in[7];
    const float* dWhh = (const float*)d_in[8];
    const float* dbih = (const float*)d_in[9];
    const float* dbhh = (const float*)d_in[10];
    const float* fcW  = (const float*)d_in[11];
    const float* fcb  = (const float*)d_in[12];
    const int*   sos  = (const int*)d_in[13];
    float* out = (float*)d_out;

    float4* Ptu_e = (float4*)d_ws;           // 65536 f4 = 1 MB
    float4* Ptu_d = Ptu_e + 65536;           // 1 MB
    float4* Wr_e  = Ptu_d + 65536;           // 1 MB
    float4* Wr_d  = Wr_e + 65536;            // 1 MB
    float4* Fr    = Wr_d + 65536;            // 256 KB
    float*  h0d   = (float*)(Fr + 16384);    // 2 MB

    make_ptab<<<256, 256, 0, stream>>>(Ptu_e, emb, eWih, ebih, ebhh);
    make_ptab<<<256, 256, 0, stream>>>(Ptu_d, emb, dWih, dbih, dbhh);
    pack_wr<<<256, 256, 0, stream>>>(Wr_e, eWhh);
    pack_wr<<<256, 256, 0, stream>>>(Wr_d, dWhh);
    pack_fr<<<64, 256, 0, stream>>>(Fr, fcW);
    enc_kernel<<<NWG, NT, 0, stream>>>(Wr_e, Ptu_e, phon, lens, h0d);
    dec_kernel<<<NWG, NT, 0, stream>>>(Wr_d, Fr, Ptu_d, fcb, h0d, sos, out);
}

// Round 3
// 1925.980 us; speedup vs baseline: 1.6431x; 1.6431x over previous
//
#include <hip/hip_runtime.h>
#include <math.h>

#define Hn   256
#define En   128
#define Vn   256
#define TPn  32
#define BTn  2048
#define NSV  8              // seqs per WG
#define NWG  (BTn / NSV)    // 256 workgroups
#define NT   1024           // 16 waves
#define HROW 272            // padded LDS row stride (floats) for h
#define SROW 260            // padded LDS row stride for score stage

// Grid = 256 WGs on 256 CUs -> exactly 1 block/CU = 4 waves/EU. Occupancy is
// fixed by launch geometry, so pin the allocator at 4 waves/EU (128 VGPR cap):
// with only a min bound it targets 8 waves/EU = 64 VGPRs and SPILLS (R1/R2:
// 3 GB of scratch traffic). waves_per_eu(4,4) removes that incentive.
#define KATTR __attribute__((amdgpu_waves_per_eu(4, 4)))

// physical index within an h row: +4 float skew per 64-chunk (conflict-free quads)
__device__ __forceinline__ int hp(int k) { return k + 4 * (k >> 6); }

__device__ __forceinline__ float sigf(float x) {
    return __builtin_amdgcn_rcpf(1.0f + __expf(-x));
}
__device__ __forceinline__ float tanh_fast(float x) {
    float e = __expf(2.0f * x);
    return 1.0f - 2.0f * __builtin_amdgcn_rcpf(e + 1.0f);
}

__device__ __forceinline__ unsigned long long amax_key(float sc, int v) {
    unsigned fb = __float_as_uint(sc);
    fb = (fb & 0x80000000u) ? ~fb : (fb | 0x80000000u);   // order-preserving
    return ((unsigned long long)fb << 32) | (unsigned)(Vn - 1 - v);  // first-idx tie
}
__device__ __forceinline__ float dot4(float4 a, float4 b, float acc) {
    return fmaf(a.x, b.x, fmaf(a.y, b.y, fmaf(a.z, b.z, fmaf(a.w, b.w, acc))));
}

// Butterfly reduce-scatter over the 4 K-chunk lanes (ch = lane&3).
// In: v[0..7] = partial sums for seqs 0..7 (this lane's K-chunk).
// Out: a = full sum for seq 2ch, b = full sum for seq 2ch+1. Static regs only.
__device__ __forceinline__ void rs8(const float v[8], int ch, float& a, float& b) {
    const bool hi2 = (ch & 2) != 0;
    float w0, w1, w2, w3;
    { float s = hi2 ? v[0] : v[4]; float r = __shfl_xor(s, 2, 64); w0 = (hi2 ? v[4] : v[0]) + r; }
    { float s = hi2 ? v[1] : v[5]; float r = __shfl_xor(s, 2, 64); w1 = (hi2 ? v[5] : v[1]) + r; }
    { float s = hi2 ? v[2] : v[6]; float r = __shfl_xor(s, 2, 64); w2 = (hi2 ? v[6] : v[2]) + r; }
    { float s = hi2 ? v[3] : v[7]; float r = __shfl_xor(s, 2, 64); w3 = (hi2 ? v[7] : v[3]) + r; }
    const bool hi1 = (ch & 1) != 0;
    { float s = hi1 ? w0 : w2; float r = __shfl_xor(s, 1, 64); a = (hi1 ? w2 : w0) + r; }
    { float s = hi1 ? w1 : w3; float r = __shfl_xor(s, 1, 64); b = (hi1 ? w3 : w1) + r; }
}

// ---------------- staged-load / compute macros (static reg tiles) ----------------
#define ELOAD(W, j) do { \
        W[0] = Wr[((j) * 4 + 0) * NT + tid]; \
        W[1] = Wr[((j) * 4 + 1) * NT + tid]; \
        W[2] = Wr[((j) * 4 + 2) * NT + tid]; \
        W[3] = Wr[((j) * 4 + 3) * NT + tid]; \
    } while (0)
#define ESTEP(W, j) do { \
        _Pragma("unroll") \
        for (int s = 0; s < 8; ++s) { \
            float4 hv = *(const float4*)&hb[s * HROW + 4 * (j)]; \
            ag[0][s] = dot4(W[0], hv, ag[0][s]); \
            ag[1][s] = dot4(W[1], hv, ag[1][s]); \
            ag[2][s] = dot4(W[2], hv, ag[2][s]); \
            ag[3][s] = dot4(W[3], hv, ag[3][s]); \
        } \
    } while (0)
#define DLOADW(W, F, j) do { \
        W[0] = Wr[((j) * 4 + 0) * NT + tid]; \
        W[1] = Wr[((j) * 4 + 1) * NT + tid]; \
        W[2] = Wr[((j) * 4 + 2) * NT + tid]; \
        W[3] = Wr[((j) * 4 + 3) * NT + tid]; \
        F    = Fr[(j) * NT + tid]; \
    } while (0)
#define DLOADF(F, j) do { F = Fr[(j) * NT + tid]; } while (0)
#define DSTEP(W, F, j) do { \
        _Pragma("unroll") \
        for (int s = 0; s < 8; ++s) { \
            float4 hv = *(const float4*)&hb[s * HROW + 4 * (j)]; \
            ag[0][s] = dot4(W[0], hv, ag[0][s]); \
            ag[1][s] = dot4(W[1], hv, ag[1][s]); \
            ag[2][s] = dot4(W[2], hv, ag[2][s]); \
            ag[3][s] = dot4(W[3], hv, ag[3][s]); \
            af[s]    = dot4(F,  hv, af[s]); \
        } \
    } while (0)
#define FSTEP(F, j) do { \
        _Pragma("unroll") \
        for (int s = 0; s < 8; ++s) { \
            float4 hv = *(const float4*)&hb[s * HROW + 4 * (j)]; \
            af[s] = dot4(F, hv, af[s]); \
        } \
    } while (0)

// ---------------- precompute kernels ----------------

// Ptu[v*256+u] = float4{i,f,g,o}: emb[v]@Wih[g*256+u]^T + bih + bhh
__global__ void make_ptab(float4* __restrict__ Pp, const float* __restrict__ emb,
                          const float* __restrict__ Wih, const float* __restrict__ bih,
                          const float* __restrict__ bhh) {
    int v = blockIdx.x, u = threadIdx.x;
    __shared__ __align__(16) float es[En];
    if (u < En) es[u] = emb[v * En + u];
    __syncthreads();
    float a[4];
#pragma unroll
    for (int g = 0; g < 4; ++g) {
        int r = g * Hn + u;
        float acc = bih[r] + bhh[r];
        const float4* w4 = (const float4*)(Wih + r * En);
        const float4* e4 = (const float4*)es;
        for (int k = 0; k < En / 4; ++k) acc = dot4(w4[k], e4[k], acc);
        a[g] = acc;
    }
    Pp[v * Hn + u] = make_float4(a[0], a[1], a[2], a[3]);
}

// Wr[(j4*4+g)*1024 + (u*4+ch)] = float4{ Whh[g*256+u][ch*64+4j4 .. +3] }. 65536 f4.
__global__ void pack_wr(float4* __restrict__ Wr, const float* __restrict__ W) {
    int idx = blockIdx.x * 256 + threadIdx.x;
    int l = idx & 1023, stripe = idx >> 10;     // stripe 0..63
    int j4 = stripe >> 2, g = stripe & 3;
    int u = l >> 2, ch = l & 3;
    const float* s = W + (g * Hn + u) * Hn + ch * 64 + 4 * j4;
    Wr[idx] = make_float4(s[0], s[1], s[2], s[3]);
}

// Fr[j4*1024 + (u*4+ch)] = float4{ fcW[u][ch*64+4j4 .. +3] }. 16384 f4.
__global__ void pack_fr(float4* __restrict__ Fr, const float* __restrict__ W) {
    int idx = blockIdx.x * 256 + threadIdx.x;
    int l = idx & 1023, j4 = idx >> 10;
    int u = l >> 2, ch = l & 3;
    const float* s = W + u * Hn + ch * 64 + 4 * j4;
    Fr[idx] = make_float4(s[0], s[1], s[2], s[3]);
}

// ---------------- encoder ----------------
// 256 WGs x 1024 thr. Thread (u=tid>>2, ch=tid&3): gate rows 4u..4u+3 over
// K-chunk ch for all 8 seqs; reduce-scatter -> seqs {2ch,2ch+1} lane-local.
__global__ __launch_bounds__(NT) KATTR void enc_kernel(
    const float4* __restrict__ Wr, const float4* __restrict__ Ptu,
    const int* __restrict__ phon, const int* __restrict__ lens,
    float* __restrict__ h0dec) {
    const int tid = threadIdx.x, wg = blockIdx.x;
    const int u = tid >> 2, ch = tid & 3;
    const int sA = 2 * ch, sB = 2 * ch + 1;
    __shared__ __align__(16) float hs[NSV * HROW];
    __shared__ int lsh[NSV];

    for (int i = tid; i < NSV * HROW; i += NT) hs[i] = 0.0f;
    if (tid < NSV) lsh[tid] = lens[wg * NSV + tid];

    float4 wsA[4], wsB[4];
    ELOAD(wsA, 0);                      // prefetch first tile (regs stay valid across barrier)
    float cA = 0.f, cB = 0.f;
    __syncthreads();
    int mx = 0;
#pragma unroll
    for (int i = 0; i < NSV; ++i) mx = max(mx, lsh[i]);
    const int lenA = lsh[sA], lenB = lsh[sB];

    for (int t = 0; t < mx; ++t) {
        const int tokA = phon[(wg * NSV + sA) * TPn + t];
        const int tokB = phon[(wg * NSV + sB) * TPn + t];
        const float4 pA = Ptu[tokA * Hn + u];      // hidden by K-loop
        const float4 pB = Ptu[tokB * Hn + u];
        float ag[4][8];
#pragma unroll
        for (int g = 0; g < 4; ++g)
#pragma unroll
            for (int s = 0; s < 8; ++s) ag[g][s] = 0.0f;
        const float* hb = hs + ch * 68;
#pragma unroll 2
        for (int jp = 0; jp < 8; ++jp) {
            const int j0 = 2 * jp, j1 = 2 * jp + 1;
            ELOAD(wsB, j1);                 // issue j1 while computing j0
            ESTEP(wsA, j0);
            ELOAD(wsA, (j1 + 1) & 15);      // jp==7: prefetch next t's j=0 (same data every t)
            ESTEP(wsB, j1);
        }
        float gA[4], gB[4];
#pragma unroll
        for (int g = 0; g < 4; ++g) rs8(ag[g], ch, gA[g], gB[g]);
        __syncthreads();   // all K-reads of hs done
        float hA, hB;
        {
            float gi = sigf(gA[0] + pA.x), gf = sigf(gA[1] + pA.y);
            float gg = tanh_fast(gA[2] + pA.z), go = sigf(gA[3] + pA.w);
            cA = fmaf(gf, cA, gi * gg); hA = go * tanh_fast(cA);
        }
        {
            float gi = sigf(gB[0] + pB.x), gf = sigf(gB[1] + pB.y);
            float gg = tanh_fast(gB[2] + pB.z), go = sigf(gB[3] + pB.w);
            cB = fmaf(gf, cB, gi * gg); hB = go * tanh_fast(cB);
        }
        const int pu = hp(u);
        hs[sA * HROW + pu] = hA;
        hs[sB * HROW + pu] = hB;
        if (t == lenA - 1) h0dec[(wg * NSV + sA) * Hn + u] = hA;
        if (t == lenB - 1) h0dec[(wg * NSV + sB) * Hn + u] = hB;
        __syncthreads();   // new h visible
    }
}

// ---------------- decoder ----------------
// Iteration i: fc(h_i) -> scores_{i-1} -> argmax -> tok_i; gates(h_i,tok_i) -> h_{i+1}.
__global__ __launch_bounds__(NT) KATTR void dec_kernel(
    const float4* __restrict__ Wr, const float4* __restrict__ Fr,
    const float4* __restrict__ Ptu, const float* __restrict__ fcb,
    const float* __restrict__ h0dec, const int* __restrict__ sosp,
    float* __restrict__ out) {
    const int tid = threadIdx.x, wg = blockIdx.x;
    const int u = tid >> 2, ch = tid & 3;
    const int sA = 2 * ch, sB = 2 * ch + 1;
    const int wv = tid >> 6, ln = tid & 63;
    __shared__ __align__(16) float hs[NSV * HROW];
    __shared__ __align__(16) float scx[NSV * SROW];
    __shared__ unsigned long long kex[16][NSV];
    __shared__ int toks[NSV];

    {   // stage h0
        int s = tid >> 7, k = (tid & 127) * 2;
        float2 v = *(const float2*)&h0dec[(wg * NSV + s) * Hn + k];
        int pk = hp(k);
        hs[s * HROW + pk] = v.x;
        hs[s * HROW + pk + 1] = v.y;
    }
    if (tid < NSV) toks[tid] = sosp[0];
    const float fb = fcb[u];

    float4 wsA[4], wsB[4], fsA, fsB;
    DLOADW(wsA, fsA, 0);                // prefetch first tile
    float cA = 0.f, cB = 0.f;
    __syncthreads();

    for (int i = 0; i <= TPn; ++i) {
        const bool full = (i < TPn);
        float ag[4][8], af[8];
#pragma unroll
        for (int g = 0; g < 4; ++g)
#pragma unroll
            for (int s = 0; s < 8; ++s) ag[g][s] = 0.0f;
#pragma unroll
        for (int s = 0; s < 8; ++s) af[s] = 0.0f;
        const float* hb = hs + ch * 68;
        if (full) {
#pragma unroll 2
            for (int jp = 0; jp < 8; ++jp) {
                const int j0 = 2 * jp, j1 = 2 * jp + 1;
                DLOADW(wsB, fsB, j1);
                DSTEP(wsA, fsA, j0);
                DLOADW(wsA, fsA, (j1 + 1) & 15);   // jp==7: prefetch next iter's j=0
                DSTEP(wsB, fsB, j1);
            }
        } else {   // last iteration: fc only (fsA holds j=0 from previous iter's wrap)
#pragma unroll 2
            for (int jp = 0; jp < 8; ++jp) {
                const int j0 = 2 * jp, j1 = 2 * jp + 1;
                DLOADF(fsB, j1);
                FSTEP(fsA, j0);
                DLOADF(fsA, (j1 + 1) & 15);
                FSTEP(fsB, j1);
            }
        }
        float gA[4], gB[4], fA, fB;
#pragma unroll
        for (int g = 0; g < 4; ++g) rs8(ag[g], ch, gA[g], gB[g]);
        rs8(af, ch, fA, fB);

        if (i > 0) {   // scores_{i-1} for v=u, seqs sA,sB
            float scA = fA + fb, scB = fB + fb;
            scx[sA * SROW + u] = scA;
            scx[sB * SROW + u] = scB;
            unsigned long long kA = amax_key(scA, u);
            unsigned long long kB = amax_key(scB, u);
#pragma unroll
            for (int off = 4; off < 64; off <<= 1) {
                unsigned long long oA = __shfl_xor(kA, off, 64);
                unsigned long long oB = __shfl_xor(kB, off, 64);
                if (oA > kA) kA = oA;
                if (oB > kB) kB = oB;
            }
            if (ln < 4) {          // ln==ch here
                kex[wv][sA] = kA;
                kex[wv][sB] = kB;
            }
        }
        __syncthreads();   // hs reads done; scx/kex published

        if (i > 0) {
            if (tid < NSV) {       // global argmax per seq
                unsigned long long k = kex[0][tid];
#pragma unroll
                for (int w = 1; w < 16; ++w)
                    if (kex[w][tid] > k) k = kex[w][tid];
                toks[tid] = (Vn - 1) - (int)(k & 0xffffffffu);
            }
            {   // coalesced out store of scores_{i-1}
                int s = tid >> 7, k = (tid & 127) * 2;
                float2 v = *(const float2*)&scx[s * SROW + k];
                *(float2*)&out[((long)(wg * NSV + s) * TPn + (i - 1)) * Vn + k] = v;
            }
        }
        __syncthreads();   // toks visible

        if (full) {
            const int tokA = toks[sA], tokB = toks[sB];
            const float4 pA = Ptu[tokA * Hn + u];
            const float4 pB = Ptu[tokB * Hn + u];
            float hA, hB;
            {
                float gi = sigf(gA[0] + pA.x), gf = sigf(gA[1] + pA.y);
                float gg = tanh_fast(gA[2] + pA.z), go = sigf(gA[3] + pA.w);
                cA = fmaf(gf, cA, gi * gg); hA = go * tanh_fast(cA);
            }
            {
                float gi = sigf(gB[0] + pB.x), gf = sigf(gB[1] + pB.y);
                float gg = tanh_fast(gB[2] + pB.z), go = sigf(gB[3] + pB.w);
                cB = fmaf(gf, cB, gi * gg); hB = go * tanh_fast(cB);
            }
            const int pu = hp(u);
            hs[sA * HROW + pu] = hA;
            hs[sB * HROW + pu] = hB;
        }
        __syncthreads();   // new h visible
    }
}

// ---------------- launch ----------------
extern "C" void kernel_launch(void* const* d_in, const int* in_sizes, int n_in,
                              void* d_out, int out_size, void* d_ws, size_t ws_size,
                              hipStream_t stream) {
    const int*   phon = (const int*)d_in[0];
    const int*   lens = (const int*)d_in[1];
    const float* emb  = (const float*)d_in[2];
    const float* eWih = (const float*)d_in[3];
    const float* eWhh = (const float*)d_in[4];
    const float* ebih = (const float*)d_in[5];
    const float* ebhh = (const float*)d_in[6];
    const float* dWih = (const float*)d_in[7];
    const float* dWhh = (const float*)d_in[8];
    const float* dbih = (const float*)d_in[9];
    const float* dbhh = (const float*)d_in[10];
    const float* fcW  = (const float*)d_in[11];
    const float* fcb  = (const float*)d_in[12];
    const int*   sos  = (const int*)d_in[13];
    float* out = (float*)d_out;

    float4* Ptu_e = (float4*)d_ws;           // 65536 f4 = 1 MB
    float4* Ptu_d = Ptu_e + 65536;           // 1 MB
    float4* Wr_e  = Ptu_d + 65536;           // 1 MB
    float4* Wr_d  = Wr_e + 65536;            // 1 MB
    float4* Fr    = Wr_d + 65536;            // 256 KB
    float*  h0d   = (float*)(Fr + 16384);    // 2 MB

    make_ptab<<<256, 256, 0, stream>>>(Ptu_e, emb, eWih, ebih, ebhh);
    make_ptab<<<256, 256, 0, stream>>>(Ptu_d, emb, dWih, dbih, dbhh);
    pack_wr<<<256, 256, 0, stream>>>(Wr_e, eWhh);
    pack_wr<<<256, 256, 0, stream>>>(Wr_d, dWhh);
    pack_fr<<<64, 256, 0, stream>>>(Fr, fcW);
    enc_kernel<<<NWG, NT, 0, stream>>>(Wr_e, Ptu_e, phon, lens, h0d);
    dec_kernel<<<NWG, NT, 0, stream>>>(Wr_d, Fr, Ptu_d, fcb, h0d, sos, out);
}

// Round 5
// 1417.927 us; speedup vs baseline: 2.2319x; 1.3583x over previous
//
#include <hip/hip_runtime.h>
#include <math.h>

#define Hn   256
#define En   128
#define Vn   256
#define TPn  32
#define BTn  2048
#define NSV  8              // seqs per WG
#define NWG  (BTn / NSV)    // 256 workgroups
#define NT   1024           // 16 waves
#define HROW 272            // padded LDS row stride (floats) for h
#define SROW 260            // padded LDS row stride for score stage

// Grid = 256 WGs on 256 CUs -> exactly 1 block/CU = 4 waves/EU, fixed by
// launch geometry. R3 showed waves_per_eu(4,4) alone is dropped (VGPR stuck
// at 64): HIP's default flat-work-group-size is {1,1024}, making the 4/EU
// request infeasible for small hypothetical blocks, so the backend ignores
// it. Pinning the WG size to exactly 1024 makes the pair consistent and
// should raise the VGPR budget to 128.
#define KATTR __attribute__((amdgpu_flat_work_group_size(1024, 1024), amdgpu_waves_per_eu(4, 4)))

// physical index within an h row: +4 float skew per 64-chunk (conflict-free quads)
__device__ __forceinline__ int hp(int k) { return k + 4 * (k >> 6); }

__device__ __forceinline__ float sigf(float x) {
    return __builtin_amdgcn_rcpf(1.0f + __expf(-x));
}
__device__ __forceinline__ float tanh_fast(float x) {
    float e = __expf(2.0f * x);
    return 1.0f - 2.0f * __builtin_amdgcn_rcpf(e + 1.0f);
}

__device__ __forceinline__ unsigned long long amax_key(float sc, int v) {
    unsigned fb = __float_as_uint(sc);
    fb = (fb & 0x80000000u) ? ~fb : (fb | 0x80000000u);   // order-preserving
    return ((unsigned long long)fb << 32) | (unsigned)(Vn - 1 - v);  // first-idx tie
}
__device__ __forceinline__ float dot4(float4 a, float4 b, float acc) {
    return fmaf(a.x, b.x, fmaf(a.y, b.y, fmaf(a.z, b.z, fmaf(a.w, b.w, acc))));
}

// Butterfly reduce-scatter over the 4 K-chunk lanes (ch = lane&3).
// In: v[0..7] = partial sums for seqs 0..7 (this lane's K-chunk).
// Out: a = full sum for seq 2ch, b = full sum for seq 2ch+1. Static regs only.
__device__ __forceinline__ void rs8(const float v[8], int ch, float& a, float& b) {
    const bool hi2 = (ch & 2) != 0;
    float w0, w1, w2, w3;
    { float s = hi2 ? v[0] : v[4]; float r = __shfl_xor(s, 2, 64); w0 = (hi2 ? v[4] : v[0]) + r; }
    { float s = hi2 ? v[1] : v[5]; float r = __shfl_xor(s, 2, 64); w1 = (hi2 ? v[5] : v[1]) + r; }
    { float s = hi2 ? v[2] : v[6]; float r = __shfl_xor(s, 2, 64); w2 = (hi2 ? v[6] : v[2]) + r; }
    { float s = hi2 ? v[3] : v[7]; float r = __shfl_xor(s, 2, 64); w3 = (hi2 ? v[7] : v[3]) + r; }
    const bool hi1 = (ch & 1) != 0;
    { float s = hi1 ? w0 : w2; float r = __shfl_xor(s, 1, 64); a = (hi1 ? w2 : w0) + r; }
    { float s = hi1 ? w1 : w3; float r = __shfl_xor(s, 1, 64); b = (hi1 ? w3 : w1) + r; }
}

// ---------------- precompute kernels ----------------

// Ptu[v*256+u] = float4{i,f,g,o}: emb[v]@Wih[g*256+u]^T + bih + bhh
__global__ void make_ptab(float4* __restrict__ Pp, const float* __restrict__ emb,
                          const float* __restrict__ Wih, const float* __restrict__ bih,
                          const float* __restrict__ bhh) {
    int v = blockIdx.x, u = threadIdx.x;
    __shared__ __align__(16) float es[En];
    if (u < En) es[u] = emb[v * En + u];
    __syncthreads();
    float a[4];
#pragma unroll
    for (int g = 0; g < 4; ++g) {
        int r = g * Hn + u;
        float acc = bih[r] + bhh[r];
        const float4* w4 = (const float4*)(Wih + r * En);
        const float4* e4 = (const float4*)es;
        for (int k = 0; k < En / 4; ++k) acc = dot4(w4[k], e4[k], acc);
        a[g] = acc;
    }
    Pp[v * Hn + u] = make_float4(a[0], a[1], a[2], a[3]);
}

// Wr[(j4*4+g)*1024 + (u*4+ch)] = float4{ Whh[g*256+u][ch*64+4j4 .. +3] }. 65536 f4.
__global__ void pack_wr(float4* __restrict__ Wr, const float* __restrict__ W) {
    int idx = blockIdx.x * 256 + threadIdx.x;
    int l = idx & 1023, stripe = idx >> 10;     // stripe 0..63
    int j4 = stripe >> 2, g = stripe & 3;
    int u = l >> 2, ch = l & 3;
    const float* s = W + (g * Hn + u) * Hn + ch * 64 + 4 * j4;
    Wr[idx] = make_float4(s[0], s[1], s[2], s[3]);
}

// Fr[j4*1024 + (u*4+ch)] = float4{ fcW[u][ch*64+4j4 .. +3] }. 16384 f4.
__global__ void pack_fr(float4* __restrict__ Fr, const float* __restrict__ W) {
    int idx = blockIdx.x * 256 + threadIdx.x;
    int l = idx & 1023, j4 = idx >> 10;
    int u = l >> 2, ch = l & 3;
    const float* s = W + u * Hn + ch * 64 + 4 * j4;
    Fr[idx] = make_float4(s[0], s[1], s[2], s[3]);
}

// ---------------- encoder ----------------
// 256 WGs x 1024 thr. Thread (u=tid>>2, ch=tid&3): gate rows 4u..4u+3 over
// K-chunk ch for all 8 seqs; reduce-scatter -> seqs {2ch,2ch+1} lane-local.
__global__ KATTR void enc_kernel(
    const float4* __restrict__ Wr, const float4* __restrict__ Ptu,
    const int* __restrict__ phon, const int* __restrict__ lens,
    float* __restrict__ h0dec) {
    const int tid = threadIdx.x, wg = blockIdx.x;
    const int u = tid >> 2, ch = tid & 3;
    const int sA = 2 * ch, sB = 2 * ch + 1;
    __shared__ __align__(16) float hs[NSV * HROW];
    __shared__ int lsh[NSV];

    for (int i = tid; i < NSV * HROW; i += NT) hs[i] = 0.0f;
    if (tid < NSV) lsh[tid] = lens[wg * NSV + tid];
    float cA = 0.f, cB = 0.f;
    __syncthreads();
    int mx = 0;
#pragma unroll
    for (int i = 0; i < NSV; ++i) mx = max(mx, lsh[i]);
    const int lenA = lsh[sA], lenB = lsh[sB];

    for (int t = 0; t < mx; ++t) {
        const int tokA = phon[(wg * NSV + sA) * TPn + t];
        const int tokB = phon[(wg * NSV + sB) * TPn + t];
        const float4 pA = Ptu[tokA * Hn + u];      // prefetched; hidden by K-loop
        const float4 pB = Ptu[tokB * Hn + u];
        float ag[4][8];
#pragma unroll
        for (int g = 0; g < 4; ++g)
#pragma unroll
            for (int s = 0; s < 8; ++s) ag[g][s] = 0.0f;
        const float* hb = hs + ch * 68;
#pragma unroll 4
        for (int j4 = 0; j4 < 16; ++j4) {
            float4 w0 = Wr[(j4 * 4 + 0) * NT + tid];
            float4 w1 = Wr[(j4 * 4 + 1) * NT + tid];
            float4 w2 = Wr[(j4 * 4 + 2) * NT + tid];
            float4 w3 = Wr[(j4 * 4 + 3) * NT + tid];
#pragma unroll
            for (int s = 0; s < 8; ++s) {
                float4 hv = *(const float4*)&hb[s * HROW + 4 * j4];
                ag[0][s] = dot4(w0, hv, ag[0][s]);
                ag[1][s] = dot4(w1, hv, ag[1][s]);
                ag[2][s] = dot4(w2, hv, ag[2][s]);
                ag[3][s] = dot4(w3, hv, ag[3][s]);
            }
        }
        float gA[4], gB[4];
#pragma unroll
        for (int g = 0; g < 4; ++g) rs8(ag[g], ch, gA[g], gB[g]);
        __syncthreads();   // all K-reads of hs done
        float hA, hB;
        {
            float gi = sigf(gA[0] + pA.x), gf = sigf(gA[1] + pA.y);
            float gg = tanh_fast(gA[2] + pA.z), go = sigf(gA[3] + pA.w);
            cA = fmaf(gf, cA, gi * gg); hA = go * tanh_fast(cA);
        }
        {
            float gi = sigf(gB[0] + pB.x), gf = sigf(gB[1] + pB.y);
            float gg = tanh_fast(gB[2] + pB.z), go = sigf(gB[3] + pB.w);
            cB = fmaf(gf, cB, gi * gg); hB = go * tanh_fast(cB);
        }
        const int pu = hp(u);
        hs[sA * HROW + pu] = hA;
        hs[sB * HROW + pu] = hB;
        if (t == lenA - 1) h0dec[(wg * NSV + sA) * Hn + u] = hA;
        if (t == lenB - 1) h0dec[(wg * NSV + sB) * Hn + u] = hB;
        __syncthreads();   // new h visible
    }
}

// ---------------- decoder ----------------
// Iteration i: fc(h_i) -> scores_{i-1} -> argmax -> tok_i; gates(h_i,tok_i) -> h_{i+1}.
// Two barriers/iter: argmax via parity-double-buffered LDS atomicMax (u64 keys).
__global__ KATTR void dec_kernel(
    const float4* __restrict__ Wr, const float4* __restrict__ Fr,
    const float4* __restrict__ Ptu, const float* __restrict__ fcb,
    const float* __restrict__ h0dec, const int* __restrict__ sosp,
    float* __restrict__ out) {
    const int tid = threadIdx.x, wg = blockIdx.x;
    const int u = tid >> 2, ch = tid & 3;
    const int sA = 2 * ch, sB = 2 * ch + 1;
    const int ln = tid & 63;
    __shared__ __align__(16) float hs[NSV * HROW];
    __shared__ __align__(16) float scx[NSV * SROW];
    __shared__ unsigned long long gmax[2][NSV];

    {   // stage h0
        int s = tid >> 7, k = (tid & 127) * 2;
        float2 v = *(const float2*)&h0dec[(wg * NSV + s) * Hn + k];
        int pk = hp(k);
        hs[s * HROW + pk] = v.x;
        hs[s * HROW + pk + 1] = v.y;
    }
    if (tid < 2 * NSV) ((unsigned long long*)gmax)[tid] = 0ull;
    const int sos0 = sosp[0];
    const float fb = fcb[u];
    float cA = 0.f, cB = 0.f;
    __syncthreads();

    for (int i = 0; i <= TPn; ++i) {
        const bool full = (i < TPn);
        float ag[4][8], af[8];
#pragma unroll
        for (int g = 0; g < 4; ++g)
#pragma unroll
            for (int s = 0; s < 8; ++s) ag[g][s] = 0.0f;
#pragma unroll
        for (int s = 0; s < 8; ++s) af[s] = 0.0f;
        const float* hb = hs + ch * 68;
        if (full) {
#pragma unroll 4
            for (int j4 = 0; j4 < 16; ++j4) {
                float4 w0 = Wr[(j4 * 4 + 0) * NT + tid];
                float4 w1 = Wr[(j4 * 4 + 1) * NT + tid];
                float4 w2 = Wr[(j4 * 4 + 2) * NT + tid];
                float4 w3 = Wr[(j4 * 4 + 3) * NT + tid];
                float4 f = Fr[j4 * NT + tid];
#pragma unroll
                for (int s = 0; s < 8; ++s) {
                    float4 hv = *(const float4*)&hb[s * HROW + 4 * j4];
                    ag[0][s] = dot4(w0, hv, ag[0][s]);
                    ag[1][s] = dot4(w1, hv, ag[1][s]);
                    ag[2][s] = dot4(w2, hv, ag[2][s]);
                    ag[3][s] = dot4(w3, hv, ag[3][s]);
                    af[s] = dot4(f, hv, af[s]);
                }
            }
        } else {   // last iteration: fc only
#pragma unroll 4
            for (int j4 = 0; j4 < 16; ++j4) {
                float4 f = Fr[j4 * NT + tid];
#pragma unroll
                for (int s = 0; s < 8; ++s) {
                    float4 hv = *(const float4*)&hb[s * HROW + 4 * j4];
                    af[s] = dot4(f, hv, af[s]);
                }
            }
        }
        float gA[4], gB[4], fA, fB;
#pragma unroll
        for (int g = 0; g < 4; ++g) rs8(ag[g], ch, gA[g], gB[g]);
        rs8(af, ch, fA, fB);

        if (i > 0) {   // scores_{i-1} for v=u, seqs sA,sB
            float scA = fA + fb, scB = fB + fb;
            scx[sA * SROW + u] = scA;
            scx[sB * SROW + u] = scB;
            unsigned long long kA = amax_key(scA, u);
            unsigned long long kB = amax_key(scB, u);
#pragma unroll
            for (int off = 4; off < 64; off <<= 1) {
                unsigned long long oA = __shfl_xor(kA, off, 64);
                unsigned long long oB = __shfl_xor(kB, off, 64);
                if (oA > kA) kA = oA;
                if (oB > kB) kB = oB;
            }
            if (ln < 4) {          // ln==ch: one representative per wave per seq pair
                atomicMax(&gmax[i & 1][sA], kA);
                atomicMax(&gmax[i & 1][sB], kB);
            }
        }
        __syncthreads();   // bar1: hs reads done; scx + gmax[i&1] visible

        int tokA = sos0, tokB = sos0;
        if (i > 0) {
            {   // coalesced out store of scores_{i-1}
                int s = tid >> 7, k = (tid & 127) * 2;
                float2 v = *(const float2*)&scx[s * SROW + k];
                *(float2*)&out[((long)(wg * NSV + s) * TPn + (i - 1)) * Vn + k] = v;
            }
            tokA = (Vn - 1) - (int)(gmax[i & 1][sA] & 0xffffffffu);
            tokB = (Vn - 1) - (int)(gmax[i & 1][sB] & 0xffffffffu);
            if (tid < NSV) gmax[(i + 1) & 1][tid] = 0ull;   // reset other parity slot
        }

        if (full) {
            const float4 pA = Ptu[tokA * Hn + u];
            const float4 pB = Ptu[tokB * Hn + u];
            float hA, hB;
            {
                float gi = sigf(gA[0] + pA.x), gf = sigf(gA[1] + pA.y);
                float gg = tanh_fast(gA[2] + pA.z), go = sigf(gA[3] + pA.w);
                cA = fmaf(gf, cA, gi * gg); hA = go * tanh_fast(cA);
            }
            {
                float gi = sigf(gB[0] + pB.x), gf = sigf(gB[1] + pB.y);
                float gg = tanh_fast(gB[2] + pB.z), go = sigf(gB[3] + pB.w);
                cB = fmaf(gf, cB, gi * gg); hB = go * tanh_fast(cB);
            }
            const int pu = hp(u);
            hs[sA * HROW + pu] = hA;
            hs[sB * HROW + pu] = hB;
        }
        __syncthreads();   // bar2: new h + gmax reset visible
    }
}

// ---------------- launch ----------------
extern "C" void kernel_launch(void* const* d_in, const int* in_sizes, int n_in,
                              void* d_out, int out_size, void* d_ws, size_t ws_size,
                              hipStream_t stream) {
    const int*   phon = (const int*)d_in[0];
    const int*   lens = (const int*)d_in[1];
    const float* emb  = (const float*)d_in[2];
    const float* eWih = (const float*)d_in[3];
    const float* eWhh = (const float*)d_in[4];
    const float* ebih = (const float*)d_in[5];
    const float* ebhh = (const float*)d_in[6];
    const float* dWih = (const float*)d_in[7];
    const float* dWhh = (const float*)d_in[8];
    const float* dbih = (const float*)d_in[9];
    const float* dbhh = (const float*)d_in[10];
    const float* fcW  = (const float*)d_in[11];
    const float* fcb  = (const float*)d_in[12];
    const int*   sos  = (const int*)d_in[13];
    float* out = (float*)d_out;

    float4* Ptu_e = (float4*)d_ws;           // 65536 f4 = 1 MB
    float4* Ptu_d = Ptu_e + 65536;           // 1 MB
    float4* Wr_e  = Ptu_d + 65536;           // 1 MB
    float4* Wr_d  = Wr_e + 65536;            // 1 MB
    float4* Fr    = Wr_d + 65536;            // 256 KB
    float*  h0d   = (float*)(Fr + 16384);    // 2 MB

    make_ptab<<<256, 256, 0, stream>>>(Ptu_e, emb, eWih, ebih, ebhh);
    make_ptab<<<256, 256, 0, stream>>>(Ptu_d, emb, dWih, dbih, dbhh);
    pack_wr<<<256, 256, 0, stream>>>(Wr_e, eWhh);
    pack_wr<<<256, 256, 0, stream>>>(Wr_d, dWhh);
    pack_fr<<<64, 256, 0, stream>>>(Fr, fcW);
    enc_kernel<<<NWG, NT, 0, stream>>>(Wr_e, Ptu_e, phon, lens, h0d);
    dec_kernel<<<NWG, NT, 0, stream>>>(Wr_d, Fr, Ptu_d, fcb, h0d, sos, out);
}

// Round 6
// 1039.596 us; speedup vs baseline: 3.0441x; 1.3639x over previous
//
#include <hip/hip_runtime.h>
#include <math.h>

#define Hn   256
#define En   128
#define Vn   256
#define TPn  32
#define BTn  2048
#define NSV  8              // seqs per WG
#define NWG  (BTn / NSV)    // 256 workgroups
#define NT   1024           // 16 waves
#define HR2  144            // padded LDS row stride (uint pairs) for h: 4 chunks of 36
#define SROW 260            // padded LDS row stride for score stage

#define KATTR __attribute__((amdgpu_flat_work_group_size(1024, 1024), amdgpu_waves_per_eu(4, 4)))

__device__ __forceinline__ float sigf(float x) {
    return __builtin_amdgcn_rcpf(1.0f + __expf(-x));
}
__device__ __forceinline__ float tanh_fast(float x) {
    float e = __expf(2.0f * x);
    return 1.0f - 2.0f * __builtin_amdgcn_rcpf(e + 1.0f);
}

// round-to-nearest-even f32 -> bf16 (as ushort)
__device__ __forceinline__ unsigned bf16rne(float x) {
    unsigned b = __float_as_uint(x);
    return (b + 0x7FFFu + ((b >> 16) & 1u)) >> 16;
}
__device__ __forceinline__ unsigned pk2(float a, float b) {   // elem0 -> low half
    return bf16rne(a) | (bf16rne(b) << 16);
}

// D = lo(a)*lo(b) + hi(a)*hi(b) + c   (bf16 pairs, f32 accumulate)
__device__ __forceinline__ float dot2bf(unsigned a, unsigned b, float c) {
    float d;
    asm("v_dot2_f32_bf16 %0, %1, %2, %3" : "=v"(d) : "v"(a), "v"(b), "v"(c));
    return d;
}
__device__ __forceinline__ float dot8bf(uint4 w, uint4 h, float acc) {
    acc = dot2bf(w.x, h.x, acc);
    acc = dot2bf(w.y, h.y, acc);
    acc = dot2bf(w.z, h.z, acc);
    acc = dot2bf(w.w, h.w, acc);
    return acc;
}

__device__ __forceinline__ unsigned long long amax_key(float sc, int v) {
    unsigned fb = __float_as_uint(sc);
    fb = (fb & 0x80000000u) ? ~fb : (fb | 0x80000000u);   // order-preserving
    return ((unsigned long long)fb << 32) | (unsigned)(Vn - 1 - v);  // first-idx tie
}
__device__ __forceinline__ float dot4(float4 a, float4 b, float acc) {
    return fmaf(a.x, b.x, fmaf(a.y, b.y, fmaf(a.z, b.z, fmaf(a.w, b.w, acc))));
}

// Butterfly reduce-scatter over the 4 K-chunk lanes (ch = lane&3).
__device__ __forceinline__ void rs8(const float v[8], int ch, float& a, float& b) {
    const bool hi2 = (ch & 2) != 0;
    float w0, w1, w2, w3;
    { float s = hi2 ? v[0] : v[4]; float r = __shfl_xor(s, 2, 64); w0 = (hi2 ? v[4] : v[0]) + r; }
    { float s = hi2 ? v[1] : v[5]; float r = __shfl_xor(s, 2, 64); w1 = (hi2 ? v[5] : v[1]) + r; }
    { float s = hi2 ? v[2] : v[6]; float r = __shfl_xor(s, 2, 64); w2 = (hi2 ? v[6] : v[2]) + r; }
    { float s = hi2 ? v[3] : v[7]; float r = __shfl_xor(s, 2, 64); w3 = (hi2 ? v[7] : v[3]) + r; }
    const bool hi1 = (ch & 1) != 0;
    { float s = hi1 ? w0 : w2; float r = __shfl_xor(s, 1, 64); a = (hi1 ? w2 : w0) + r; }
    { float s = hi1 ? w1 : w3; float r = __shfl_xor(s, 1, 64); b = (hi1 ? w3 : w1) + r; }
}

// ---------------- precompute kernels ----------------

// Ptu[v*256+u] = float4{i,f,g,o}: emb[v]@Wih[g*256+u]^T + bih + bhh   (full f32)
__global__ void make_ptab(float4* __restrict__ Pp, const float* __restrict__ emb,
                          const float* __restrict__ Wih, const float* __restrict__ bih,
                          const float* __restrict__ bhh) {
    int v = blockIdx.x, u = threadIdx.x;
    __shared__ __align__(16) float es[En];
    if (u < En) es[u] = emb[v * En + u];
    __syncthreads();
    float a[4];
#pragma unroll
    for (int g = 0; g < 4; ++g) {
        int r = g * Hn + u;
        float acc = bih[r] + bhh[r];
        const float4* w4 = (const float4*)(Wih + r * En);
        const float4* e4 = (const float4*)es;
        for (int k = 0; k < En / 4; ++k) acc = dot4(w4[k], e4[k], acc);
        a[g] = acc;
    }
    Pp[v * Hn + u] = make_float4(a[0], a[1], a[2], a[3]);
}

// WH[(j8*4+g)*1024 + (u*4+ch)] = 8 bf16 of Whh[g*256+u][ch*64+8*j8 .. +7]. 32768 u4.
__global__ void pack_wh(uint4* __restrict__ WH, const float* __restrict__ W) {
    int idx = blockIdx.x * 256 + threadIdx.x;
    int l = idx & 1023, stripe = idx >> 10;     // stripe 0..31
    int j8 = stripe >> 2, g = stripe & 3;
    int u = l >> 2, ch = l & 3;
    const float* s = W + (g * Hn + u) * Hn + ch * 64 + 8 * j8;
    WH[idx] = make_uint4(pk2(s[0], s[1]), pk2(s[2], s[3]), pk2(s[4], s[5]), pk2(s[6], s[7]));
}

// FH[j8*1024 + (u*4+ch)] = 8 bf16 of fcW[u][ch*64+8*j8 .. +7]. 8192 u4.
__global__ void pack_fh(uint4* __restrict__ FH, const float* __restrict__ W) {
    int idx = blockIdx.x * 256 + threadIdx.x;
    int l = idx & 1023, j8 = idx >> 10;
    int u = l >> 2, ch = l & 3;
    const float* s = W + u * Hn + ch * 64 + 8 * j8;
    FH[idx] = make_uint4(pk2(s[0], s[1]), pk2(s[2], s[3]), pk2(s[4], s[5]), pk2(s[6], s[7]));
}

// ---------------- encoder ----------------
// h kept in LDS as packed bf16 pairs (hs2[s][p], p = k/2, +4-word skew per 32).
// K-loop: v_dot2_f32_bf16 (2 MACs/inst), f32 accumulate; c-state stays f32.
__global__ KATTR void enc_kernel(
    const uint4* __restrict__ WH, const float4* __restrict__ Ptu,
    const int* __restrict__ phon, const int* __restrict__ lens,
    float* __restrict__ h0dec) {
    const int tid = threadIdx.x, wg = blockIdx.x;
    const int u = tid >> 2, ch = tid & 3;
    const int sA = 2 * ch, sB = 2 * ch + 1;
    __shared__ __align__(16) unsigned hs2[NSV * HR2];
    __shared__ int lsh[NSV];

    for (int i = tid; i < NSV * HR2; i += NT) hs2[i] = 0u;
    if (tid < NSV) lsh[tid] = lens[wg * NSV + tid];
    float cA = 0.f, cB = 0.f;
    __syncthreads();
    int mx = 0;
#pragma unroll
    for (int i = 0; i < NSV; ++i) mx = max(mx, lsh[i]);
    const int lenA = lsh[sA], lenB = lsh[sB];

    for (int t = 0; t < mx; ++t) {
        const int tokA = phon[(wg * NSV + sA) * TPn + t];
        const int tokB = phon[(wg * NSV + sB) * TPn + t];
        const float4 pA = Ptu[tokA * Hn + u];      // hidden by K-loop
        const float4 pB = Ptu[tokB * Hn + u];
        float ag[4][8];
#pragma unroll
        for (int g = 0; g < 4; ++g)
#pragma unroll
            for (int s = 0; s < 8; ++s) ag[g][s] = 0.0f;
        const unsigned* hb = hs2 + ch * 36;
#pragma unroll 4
        for (int j8 = 0; j8 < 8; ++j8) {
            uint4 w0 = WH[(j8 * 4 + 0) * NT + tid];
            uint4 w1 = WH[(j8 * 4 + 1) * NT + tid];
            uint4 w2 = WH[(j8 * 4 + 2) * NT + tid];
            uint4 w3 = WH[(j8 * 4 + 3) * NT + tid];
#pragma unroll
            for (int s = 0; s < 8; ++s) {
                uint4 hv = *(const uint4*)&hb[s * HR2 + 4 * j8];
                ag[0][s] = dot8bf(w0, hv, ag[0][s]);
                ag[1][s] = dot8bf(w1, hv, ag[1][s]);
                ag[2][s] = dot8bf(w2, hv, ag[2][s]);
                ag[3][s] = dot8bf(w3, hv, ag[3][s]);
            }
        }
        float gA[4], gB[4];
#pragma unroll
        for (int g = 0; g < 4; ++g) rs8(ag[g], ch, gA[g], gB[g]);
        __syncthreads();   // all K-reads of hs2 done
        float hA, hB;
        {
            float gi = sigf(gA[0] + pA.x), gf = sigf(gA[1] + pA.y);
            float gg = tanh_fast(gA[2] + pA.z), go = sigf(gA[3] + pA.w);
            cA = fmaf(gf, cA, gi * gg); hA = go * tanh_fast(cA);
        }
        {
            float gi = sigf(gB[0] + pB.x), gf = sigf(gB[1] + pB.y);
            float gg = tanh_fast(gB[2] + pB.z), go = sigf(gB[3] + pB.w);
            cB = fmaf(gf, cB, gi * gg); hB = go * tanh_fast(cB);
        }
        if (t == lenA - 1) h0dec[(wg * NSV + sA) * Hn + u] = hA;   // f32 handoff
        if (t == lenB - 1) h0dec[(wg * NSV + sB) * Hn + u] = hB;
        // pack h pairs (even u combines with u+1 via shfl; same wave, lane+4)
        float nA = __shfl_down(hA, 4, 64);
        float nB = __shfl_down(hB, 4, 64);
        if ((tid & 4) == 0) {
            int p = u >> 1, pp = p + 4 * (p >> 5);
            hs2[sA * HR2 + pp] = pk2(hA, nA);
            hs2[sB * HR2 + pp] = pk2(hB, nB);
        }
        __syncthreads();   // new h visible
    }
}

// ---------------- decoder ----------------
// Iteration i: fc(h_i) -> scores_{i-1} -> argmax -> tok_i; gates(h_i,tok_i) -> h_{i+1}.
// Two barriers/iter: argmax via parity-double-buffered LDS atomicMax (u64 keys).
__global__ KATTR void dec_kernel(
    const uint4* __restrict__ WH, const uint4* __restrict__ FH,
    const float4* __restrict__ Ptu, const float* __restrict__ fcb,
    const float* __restrict__ h0dec, const int* __restrict__ sosp,
    float* __restrict__ out) {
    const int tid = threadIdx.x, wg = blockIdx.x;
    const int u = tid >> 2, ch = tid & 3;
    const int sA = 2 * ch, sB = 2 * ch + 1;
    const int ln = tid & 63;
    __shared__ __align__(16) unsigned hs2[NSV * HR2];
    __shared__ __align__(16) float scx[NSV * SROW];
    __shared__ unsigned long long gmax[2][NSV];

    {   // stage h0 as bf16 pairs
        int s = tid >> 7, k2 = tid & 127;
        float2 v = *(const float2*)&h0dec[(wg * NSV + s) * Hn + 2 * k2];
        hs2[s * HR2 + k2 + 4 * (k2 >> 5)] = pk2(v.x, v.y);
    }
    if (tid < 2 * NSV) ((unsigned long long*)gmax)[tid] = 0ull;
    const int sos0 = sosp[0];
    const float fb = fcb[u];
    float cA = 0.f, cB = 0.f;
    __syncthreads();

    for (int i = 0; i <= TPn; ++i) {
        const bool full = (i < TPn);
        float ag[4][8], af[8];
#pragma unroll
        for (int g = 0; g < 4; ++g)
#pragma unroll
            for (int s = 0; s < 8; ++s) ag[g][s] = 0.0f;
#pragma unroll
        for (int s = 0; s < 8; ++s) af[s] = 0.0f;
        const unsigned* hb = hs2 + ch * 36;
        if (full) {
#pragma unroll 4
            for (int j8 = 0; j8 < 8; ++j8) {
                uint4 w0 = WH[(j8 * 4 + 0) * NT + tid];
                uint4 w1 = WH[(j8 * 4 + 1) * NT + tid];
                uint4 w2 = WH[(j8 * 4 + 2) * NT + tid];
                uint4 w3 = WH[(j8 * 4 + 3) * NT + tid];
                uint4 f  = FH[j8 * NT + tid];
#pragma unroll
                for (int s = 0; s < 8; ++s) {
                    uint4 hv = *(const uint4*)&hb[s * HR2 + 4 * j8];
                    ag[0][s] = dot8bf(w0, hv, ag[0][s]);
                    ag[1][s] = dot8bf(w1, hv, ag[1][s]);
                    ag[2][s] = dot8bf(w2, hv, ag[2][s]);
                    ag[3][s] = dot8bf(w3, hv, ag[3][s]);
                    af[s]    = dot8bf(f,  hv, af[s]);
                }
            }
        } else {   // last iteration: fc only
#pragma unroll 4
            for (int j8 = 0; j8 < 8; ++j8) {
                uint4 f = FH[j8 * NT + tid];
#pragma unroll
                for (int s = 0; s < 8; ++s) {
                    uint4 hv = *(const uint4*)&hb[s * HR2 + 4 * j8];
                    af[s] = dot8bf(f, hv, af[s]);
                }
            }
        }
        float gA[4], gB[4], fA, fB;
#pragma unroll
        for (int g = 0; g < 4; ++g) rs8(ag[g], ch, gA[g], gB[g]);
        rs8(af, ch, fA, fB);

        if (i > 0) {   // scores_{i-1} for v=u, seqs sA,sB
            float scA = fA + fb, scB = fB + fb;
            scx[sA * SROW + u] = scA;
            scx[sB * SROW + u] = scB;
            unsigned long long kA = amax_key(scA, u);
            unsigned long long kB = amax_key(scB, u);
#pragma unroll
            for (int off = 4; off < 64; off <<= 1) {
                unsigned long long oA = __shfl_xor(kA, off, 64);
                unsigned long long oB = __shfl_xor(kB, off, 64);
                if (oA > kA) kA = oA;
                if (oB > kB) kB = oB;
            }
            if (ln < 4) {          // ln==ch: one representative per wave per seq pair
                atomicMax(&gmax[i & 1][sA], kA);
                atomicMax(&gmax[i & 1][sB], kB);
            }
        }
        __syncthreads();   // bar1: hs2 reads done; scx + gmax[i&1] visible

        int tokA = sos0, tokB = sos0;
        if (i > 0) {
            {   // coalesced out store of scores_{i-1}
                int s = tid >> 7, k = (tid & 127) * 2;
                float2 v = *(const float2*)&scx[s * SROW + k];
                *(float2*)&out[((long)(wg * NSV + s) * TPn + (i - 1)) * Vn + k] = v;
            }
            tokA = (Vn - 1) - (int)(gmax[i & 1][sA] & 0xffffffffu);
            tokB = (Vn - 1) - (int)(gmax[i & 1][sB] & 0xffffffffu);
            if (tid < NSV) gmax[(i + 1) & 1][tid] = 0ull;   // reset other parity slot
        }

        if (full) {
            const float4 pA = Ptu[tokA * Hn + u];
            const float4 pB = Ptu[tokB * Hn + u];
            float hA, hB;
            {
                float gi = sigf(gA[0] + pA.x), gf = sigf(gA[1] + pA.y);
                float gg = tanh_fast(gA[2] + pA.z), go = sigf(gA[3] + pA.w);
                cA = fmaf(gf, cA, gi * gg); hA = go * tanh_fast(cA);
            }
            {
                float gi = sigf(gB[0] + pB.x), gf = sigf(gB[1] + pB.y);
                float gg = tanh_fast(gB[2] + pB.z), go = sigf(gB[3] + pB.w);
                cB = fmaf(gf, cB, gi * gg); hB = go * tanh_fast(cB);
            }
            float nA = __shfl_down(hA, 4, 64);
            float nB = __shfl_down(hB, 4, 64);
            if ((tid & 4) == 0) {
                int p = u >> 1, pp = p + 4 * (p >> 5);
                hs2[sA * HR2 + pp] = pk2(hA, nA);
                hs2[sB * HR2 + pp] = pk2(hB, nB);
            }
        }
        __syncthreads();   // bar2: new h + gmax reset visible
    }
}

// ---------------- launch ----------------
extern "C" void kernel_launch(void* const* d_in, const int* in_sizes, int n_in,
                              void* d_out, int out_size, void* d_ws, size_t ws_size,
                              hipStream_t stream) {
    const int*   phon = (const int*)d_in[0];
    const int*   lens = (const int*)d_in[1];
    const float* emb  = (const float*)d_in[2];
    const float* eWih = (const float*)d_in[3];
    const float* eWhh = (const float*)d_in[4];
    const float* ebih = (const float*)d_in[5];
    const float* ebhh = (const float*)d_in[6];
    const float* dWih = (const float*)d_in[7];
    const float* dWhh = (const float*)d_in[8];
    const float* dbih = (const float*)d_in[9];
    const float* dbhh = (const float*)d_in[10];
    const float* fcW  = (const float*)d_in[11];
    const float* fcb  = (const float*)d_in[12];
    const int*   sos  = (const int*)d_in[13];
    float* out = (float*)d_out;

    float4* Ptu_e = (float4*)d_ws;            // 65536 f4 = 1 MB
    float4* Ptu_d = Ptu_e + 65536;            // 1 MB
    uint4*  WH_e  = (uint4*)(Ptu_d + 65536);  // 32768 u4 = 512 KB
    uint4*  WH_d  = WH_e + 32768;             // 512 KB
    uint4*  FH    = WH_d + 32768;             // 8192 u4 = 128 KB
    float*  h0d   = (float*)(FH + 8192);      // 2 MB

    make_ptab<<<256, 256, 0, stream>>>(Ptu_e, emb, eWih, ebih, ebhh);
    make_ptab<<<256, 256, 0, stream>>>(Ptu_d, emb, dWih, dbih, dbhh);
    pack_wh<<<128, 256, 0, stream>>>(WH_e, eWhh);
    pack_wh<<<128, 256, 0, stream>>>(WH_d, dWhh);
    pack_fh<<<32, 256, 0, stream>>>(FH, fcW);
    enc_kernel<<<NWG, NT, 0, stream>>>(WH_e, Ptu_e, phon, lens, h0d);
    dec_kernel<<<NWG, NT, 0, stream>>>(WH_d, FH, Ptu_d, fcb, h0d, sos, out);
}

// Round 7
// 927.047 us; speedup vs baseline: 3.4137x; 1.1214x over previous
//
#include <hip/hip_runtime.h>
#include <math.h>

#define Hn   256
#define En   128
#define Vn   256
#define TPn  32
#define BTn  2048
#define NSV  8              // seqs per WG
#define NWG  (BTn / NSV)    // 256 workgroups
#define NT   1024           // 16 waves
#define SROW 260            // padded LDS row stride for score stage
#define GSTR 9              // gact row stride (floats): 8 seqs + 1 pad

#define KATTR __attribute__((amdgpu_flat_work_group_size(1024, 1024), amdgpu_waves_per_eu(4, 4)))

typedef __attribute__((ext_vector_type(8))) short bf16x8;   // 8 bf16 = 4 VGPR (guide §3)
typedef __attribute__((ext_vector_type(4))) float f32x4;

__device__ __forceinline__ float sigf(float x) {
    return __builtin_amdgcn_rcpf(1.0f + __expf(-x));
}
__device__ __forceinline__ float tanh_fast(float x) {
    float e = __expf(2.0f * x);
    return 1.0f - 2.0f * __builtin_amdgcn_rcpf(e + 1.0f);
}

// round-to-nearest-even f32 -> bf16 (as ushort)
__device__ __forceinline__ unsigned bf16rne(float x) {
    unsigned b = __float_as_uint(x);
    return (b + 0x7FFFu + ((b >> 16) & 1u)) >> 16;
}
__device__ __forceinline__ unsigned pk2(float a, float b) {   // elem0 -> low half
    return bf16rne(a) | (bf16rne(b) << 16);
}

__device__ __forceinline__ unsigned long long amax_key(float sc, int v) {
    unsigned fb = __float_as_uint(sc);
    fb = (fb & 0x80000000u) ? ~fb : (fb | 0x80000000u);   // order-preserving
    return ((unsigned long long)fb << 32) | (unsigned)(Vn - 1 - v);  // first-idx tie
}
__device__ __forceinline__ float dot4(float4 a, float4 b, float acc) {
    return fmaf(a.x, b.x, fmaf(a.y, b.y, fmaf(a.z, b.z, fmaf(a.w, b.w, acc))));
}

// ---------------- precompute kernels ----------------

// Ptu[v*256+u] = float4{i,f,g,o}: emb[v]@Wih[g*256+u]^T + bih + bhh   (full f32)
__global__ void make_ptab(float4* __restrict__ Pp, const float* __restrict__ emb,
                          const float* __restrict__ Wih, const float* __restrict__ bih,
                          const float* __restrict__ bhh) {
    int v = blockIdx.x, u = threadIdx.x;
    __shared__ __align__(16) float es[En];
    if (u < En) es[u] = emb[v * En + u];
    __syncthreads();
    float a[4];
#pragma unroll
    for (int g = 0; g < 4; ++g) {
        int r = g * Hn + u;
        float acc = bih[r] + bhh[r];
        const float4* w4 = (const float4*)(Wih + r * En);
        const float4* e4 = (const float4*)es;
        for (int k = 0; k < En / 4; ++k) acc = dot4(w4[k], e4[k], acc);
        a[g] = acc;
    }
    Pp[v * Hn + u] = make_float4(a[0], a[1], a[2], a[3]);
}

// A-fragment pack for mfma_f32_16x16x32_bf16.
// Wcat rows: 0..1023 = Whh (gate g*256+u), 1024..1279 = fcW (row v).
// A[idx], idx = (t*8+q)*64 + l  -> 8 bf16 of Wcat[16t + (l&15)][32q + 8*(l>>4) .. +7].
// IMPORTANT: the (lanegroup,j)->k map here matches the B-fragment staging in the
// main kernels, so any hardware k-slot permutation cancels (A/B consistent).
__global__ void pack_afrag(uint4* __restrict__ A, const float* __restrict__ Whh,
                           const float* __restrict__ fcW, int ntile) {
    int idx = blockIdx.x * 256 + threadIdx.x;
    if (idx >= ntile * 512) return;
    int l = idx & 63, q = (idx >> 6) & 7, t = idx >> 9;
    int r = 16 * t + (l & 15);
    int kb = 32 * q + 8 * (l >> 4);
    const float* s = (r < 1024) ? (Whh + r * Hn + kb) : (fcW + (r - 1024) * Hn + kb);
    A[idx] = make_uint4(pk2(s[0], s[1]), pk2(s[2], s[3]), pk2(s[4], s[5]), pk2(s[6], s[7]));
}

// ---------------- encoder ----------------
// Per step: G = Wcat(1024x256) x h^T(256x8) via MFMA (wave w owns 4 M-tiles),
// C -> gact LDS roundtrip -> per-(u,seq) activations -> h update -> B-frag LDS.
__global__ KATTR void enc_kernel(
    const bf16x8* __restrict__ AW, const float4* __restrict__ Ptu,
    const int* __restrict__ phon, const int* __restrict__ lens,
    float* __restrict__ h0dec) {
    const int tid = threadIdx.x, wg = blockIdx.x;
    const int wv = tid >> 6, l = tid & 63;
    const int c16 = l & 15, rg = l >> 4;
    const int u = tid >> 2, ch = tid & 3;
    const int sA = 2 * ch, sB = 2 * ch + 1;
    __shared__ __align__(16) uint4 hBf[8 * 64];      // B-fragments; cols 8..15 stay 0
    __shared__ float gact[1024 * GSTR];              // 36.9 KB
    __shared__ int lsh[NSV];

    if (tid < 512) hBf[tid] = make_uint4(0u, 0u, 0u, 0u);   // h0 = 0
    if (tid < NSV) lsh[tid] = lens[wg * NSV + tid];
    float cA = 0.f, cB = 0.f;
    __syncthreads();
    int mx = 0;
#pragma unroll
    for (int i = 0; i < NSV; ++i) mx = max(mx, lsh[i]);
    const int lenA = lsh[sA], lenB = lsh[sB];

    for (int t = 0; t < mx; ++t) {
        const int tokA = phon[(wg * NSV + sA) * TPn + t];
        const int tokB = phon[(wg * NSV + sB) * TPn + t];
        const float4 pA = Ptu[tokA * Hn + u];      // prefetched; hidden by MFMA phase
        const float4 pB = Ptu[tokB * Hn + u];

        f32x4 acc[4];
#pragma unroll
        for (int ii = 0; ii < 4; ++ii) acc[ii] = (f32x4){0.f, 0.f, 0.f, 0.f};
#pragma unroll
        for (int q = 0; q < 8; ++q) {
            bf16x8 bf = *(const bf16x8*)&hBf[q * 64 + l];
#pragma unroll
            for (int ii = 0; ii < 4; ++ii) {
                bf16x8 af = AW[((4 * wv + ii) * 8 + q) * 64 + l];
                acc[ii] = __builtin_amdgcn_mfma_f32_16x16x32_bf16(af, bf, acc[ii], 0, 0, 0);
            }
        }
        if (c16 < 8) {   // C layout: col=lane&15 (seq), row=(lane>>4)*4+reg [m89-verified]
#pragma unroll
            for (int ii = 0; ii < 4; ++ii) {
                int Rb = (4 * wv + ii) * 16 + rg * 4;
#pragma unroll
                for (int r = 0; r < 4; ++r) gact[(Rb + r) * GSTR + c16] = acc[ii][r];
            }
        }
        __syncthreads();   // bar1: gact visible; hBf reads done

        float g0A = gact[(u) * GSTR + sA],       g0B = gact[(u) * GSTR + sB];
        float g1A = gact[(256 + u) * GSTR + sA], g1B = gact[(256 + u) * GSTR + sB];
        float g2A = gact[(512 + u) * GSTR + sA], g2B = gact[(512 + u) * GSTR + sB];
        float g3A = gact[(768 + u) * GSTR + sA], g3B = gact[(768 + u) * GSTR + sB];
        float hvA, hvB;
        {
            float gi = sigf(g0A + pA.x), gf = sigf(g1A + pA.y);
            float gg = tanh_fast(g2A + pA.z), go = sigf(g3A + pA.w);
            cA = fmaf(gf, cA, gi * gg); hvA = go * tanh_fast(cA);
        }
        {
            float gi = sigf(g0B + pB.x), gf = sigf(g1B + pB.y);
            float gg = tanh_fast(g2B + pB.z), go = sigf(g3B + pB.w);
            cB = fmaf(gf, cB, gi * gg); hvB = go * tanh_fast(cB);
        }
        if (t == lenA - 1) h0dec[(wg * NSV + sA) * Hn + u] = hvA;
        if (t == lenB - 1) h0dec[(wg * NSV + sB) * Hn + u] = hvB;
        {   // write new h into B-fragment layout (k=u -> q=u>>5, g=(u>>3)&3, j=u&7)
            unsigned short* hb16 = (unsigned short*)hBf;
            int q = u >> 5, g = (u >> 3) & 3, j = u & 7;
            hb16[(q * 64 + g * 16 + sA) * 8 + j] = (unsigned short)bf16rne(hvA);
            hb16[(q * 64 + g * 16 + sB) * 8 + j] = (unsigned short)bf16rne(hvB);
        }
        __syncthreads();   // bar2: new h fragments visible
    }
}

// ---------------- decoder ----------------
// M = 1280 (1024 gates + 256 fc) fused in one MFMA pass; wave owns 5 M-tiles.
// 3 barriers/iter: gact roundtrip, argmax visibility, h-fragment publish.
__global__ KATTR void dec_kernel(
    const bf16x8* __restrict__ AW, const float4* __restrict__ Ptu,
    const float* __restrict__ fcb, const float* __restrict__ h0dec,
    const int* __restrict__ sosp, float* __restrict__ out) {
    const int tid = threadIdx.x, wg = blockIdx.x;
    const int wv = tid >> 6, l = tid & 63;
    const int c16 = l & 15, rg = l >> 4;
    const int u = tid >> 2, ch = tid & 3;
    const int sA = 2 * ch, sB = 2 * ch + 1;
    const int ln = tid & 63;
    __shared__ __align__(16) uint4 hBf[8 * 64];      // B-fragments; cols 8..15 stay 0
    __shared__ float gact[1280 * GSTR];              // 46.1 KB
    __shared__ float scx[NSV * SROW];
    __shared__ unsigned long long gmax[2][NSV];

    if (tid < 512) {   // stage h0 directly into B-fragment layout
        int q = tid >> 6, ll = tid & 63, c = ll & 15, g = ll >> 4;
        uint4 v = make_uint4(0u, 0u, 0u, 0u);
        if (c < 8) {
            const float* hp = h0dec + (wg * NSV + c) * Hn + 32 * q + 8 * g;
            float4 v0 = *(const float4*)hp;
            float4 v1 = *(const float4*)(hp + 4);
            v = make_uint4(pk2(v0.x, v0.y), pk2(v0.z, v0.w), pk2(v1.x, v1.y), pk2(v1.z, v1.w));
        }
        hBf[tid] = v;
    }
    if (tid < 2 * NSV) ((unsigned long long*)gmax)[tid] = 0ull;
    const int sos0 = sosp[0];
    const float fb = fcb[u];
    float cA = 0.f, cB = 0.f;
    __syncthreads();

    for (int i = 0; i <= TPn; ++i) {
        const bool full = (i < TPn);

        f32x4 acc[5];
#pragma unroll
        for (int ii = 0; ii < 5; ++ii) acc[ii] = (f32x4){0.f, 0.f, 0.f, 0.f};
#pragma unroll
        for (int q = 0; q < 8; ++q) {
            bf16x8 bf = *(const bf16x8*)&hBf[q * 64 + l];
#pragma unroll
            for (int ii = 0; ii < 5; ++ii) {
                bf16x8 af = AW[((5 * wv + ii) * 8 + q) * 64 + l];
                acc[ii] = __builtin_amdgcn_mfma_f32_16x16x32_bf16(af, bf, acc[ii], 0, 0, 0);
            }
        }
        if (c16 < 8) {
#pragma unroll
            for (int ii = 0; ii < 5; ++ii) {
                int Rb = (5 * wv + ii) * 16 + rg * 4;
#pragma unroll
                for (int r = 0; r < 4; ++r) gact[(Rb + r) * GSTR + c16] = acc[ii][r];
            }
        }
        __syncthreads();   // bar1: gact visible; hBf reads done

        float g0A = 0.f, g1A = 0.f, g2A = 0.f, g3A = 0.f;
        float g0B = 0.f, g1B = 0.f, g2B = 0.f, g3B = 0.f;
        if (full) {
            g0A = gact[(u) * GSTR + sA];       g0B = gact[(u) * GSTR + sB];
            g1A = gact[(256 + u) * GSTR + sA]; g1B = gact[(256 + u) * GSTR + sB];
            g2A = gact[(512 + u) * GSTR + sA]; g2B = gact[(512 + u) * GSTR + sB];
            g3A = gact[(768 + u) * GSTR + sA]; g3B = gact[(768 + u) * GSTR + sB];
        }
        if (i > 0) {   // scores_{i-1} for v=u, seqs sA,sB (fc rows 1024+v)
            float scA = gact[(1024 + u) * GSTR + sA] + fb;
            float scB = gact[(1024 + u) * GSTR + sB] + fb;
            scx[sA * SROW + u] = scA;
            scx[sB * SROW + u] = scB;
            unsigned long long kA = amax_key(scA, u);
            unsigned long long kB = amax_key(scB, u);
#pragma unroll
            for (int off = 4; off < 64; off <<= 1) {
                unsigned long long oA = __shfl_xor(kA, off, 64);
                unsigned long long oB = __shfl_xor(kB, off, 64);
                if (oA > kA) kA = oA;
                if (oB > kB) kB = oB;
            }
            if (ln < 4) {
                atomicMax(&gmax[i & 1][sA], kA);
                atomicMax(&gmax[i & 1][sB], kB);
            }
        }
        __syncthreads();   // bar2: scx + gmax visible; gact reads done

        int tokA = sos0, tokB = sos0;
        if (i > 0) {
            {   // coalesced out store of scores_{i-1}
                int s = tid >> 7, k = (tid & 127) * 2;
                float2 v = *(const float2*)&scx[s * SROW + k];
                *(float2*)&out[((long)(wg * NSV + s) * TPn + (i - 1)) * Vn + k] = v;
            }
            tokA = (Vn - 1) - (int)(gmax[i & 1][sA] & 0xffffffffu);
            tokB = (Vn - 1) - (int)(gmax[i & 1][sB] & 0xffffffffu);
            if (tid < NSV) gmax[(i + 1) & 1][tid] = 0ull;   // reset other parity slot
        }

        if (full) {
            const float4 pA = Ptu[tokA * Hn + u];
            const float4 pB = Ptu[tokB * Hn + u];
            float hvA, hvB;
            {
                float gi = sigf(g0A + pA.x), gf = sigf(g1A + pA.y);
                float gg = tanh_fast(g2A + pA.z), go = sigf(g3A + pA.w);
                cA = fmaf(gf, cA, gi * gg); hvA = go * tanh_fast(cA);
            }
            {
                float gi = sigf(g0B + pB.x), gf = sigf(g1B + pB.y);
                float gg = tanh_fast(g2B + pB.z), go = sigf(g3B + pB.w);
                cB = fmaf(gf, cB, gi * gg); hvB = go * tanh_fast(cB);
            }
            unsigned short* hb16 = (unsigned short*)hBf;
            int q = u >> 5, g = (u >> 3) & 3, j = u & 7;
            hb16[(q * 64 + g * 16 + sA) * 8 + j] = (unsigned short)bf16rne(hvA);
            hb16[(q * 64 + g * 16 + sB) * 8 + j] = (unsigned short)bf16rne(hvB);
        }
        __syncthreads();   // bar3: new h fragments + gmax reset visible
    }
}

// ---------------- launch ----------------
extern "C" void kernel_launch(void* const* d_in, const int* in_sizes, int n_in,
                              void* d_out, int out_size, void* d_ws, size_t ws_size,
                              hipStream_t stream) {
    const int*   phon = (const int*)d_in[0];
    const int*   lens = (const int*)d_in[1];
    const float* emb  = (const float*)d_in[2];
    const float* eWih = (const float*)d_in[3];
    const float* eWhh = (const float*)d_in[4];
    const float* ebih = (const float*)d_in[5];
    const float* ebhh = (const float*)d_in[6];
    const float* dWih = (const float*)d_in[7];
    const float* dWhh = (const float*)d_in[8];
    const float* dbih = (const float*)d_in[9];
    const float* dbhh = (const float*)d_in[10];
    const float* fcW  = (const float*)d_in[11];
    const float* fcb  = (const float*)d_in[12];
    const int*   sos  = (const int*)d_in[13];
    float* out = (float*)d_out;

    float4* Ptu_e = (float4*)d_ws;            // 65536 f4 = 1 MB
    float4* Ptu_d = Ptu_e + 65536;            // 1 MB
    uint4*  AW_e  = (uint4*)(Ptu_d + 65536);  // 64 tiles * 512 = 32768 u4 = 512 KB
    uint4*  AW_d  = AW_e + 32768;             // 80 tiles * 512 = 40960 u4 = 640 KB
    float*  h0d   = (float*)(AW_d + 40960);   // 2 MB

    make_ptab<<<256, 256, 0, stream>>>(Ptu_e, emb, eWih, ebih, ebhh);
    make_ptab<<<256, 256, 0, stream>>>(Ptu_d, emb, dWih, dbih, dbhh);
    pack_afrag<<<128, 256, 0, stream>>>(AW_e, eWhh, eWhh, 64);   // fcW unused (ntile=64)
    pack_afrag<<<160, 256, 0, stream>>>(AW_d, dWhh, fcW, 80);
    enc_kernel<<<NWG, NT, 0, stream>>>((const bf16x8*)AW_e, Ptu_e, phon, lens, h0d);
    dec_kernel<<<NWG, NT, 0, stream>>>((const bf16x8*)AW_d, Ptu_d, fcb, h0d, sos, out);
}